// Round 7
// baseline (54317.389 us; speedup 1.0000x reference)
//
#include <hip/hip_runtime.h>
#include <hip/hip_cooperative_groups.h>

namespace cg = cooperative_groups;

constexpr int B_ = 128, T_ = 1024, D_ = 512, U_ = 512;
constexpr int NBLK = 256, NTHR = 1024;
constexpr int G4 = 4 * U_;   // 2048 gate columns

__device__ __forceinline__ float sigm(float v) { return 1.0f / (1.0f + expf(-v)); }

#define AGENT_LD(p)    __hip_atomic_load((p), __ATOMIC_RELAXED, __HIP_MEMORY_SCOPE_AGENT)
#define AGENT_LDA(p)   __hip_atomic_load((p), __ATOMIC_ACQUIRE, __HIP_MEMORY_SCOPE_AGENT)
#define AGENT_ST(p, v) __hip_atomic_store((p), (v), __ATOMIC_RELAXED, __HIP_MEMORY_SCOPE_AGENT)

// ---------------- x[b][t][k] -> xT[t][k][b] ----------------------------------------
__global__ __launch_bounds__(256) void transpose_x(const float* __restrict__ x,
                                                   float* __restrict__ xT)
{
    __shared__ float tile[32][33];
    const int tileId = blockIdx.x;
    const int bt = tileId & 3;
    const int kt = (tileId >> 2) & 15;
    const int t  = tileId >> 6;
    const int tx = threadIdx.x & 31;
    const int ty = threadIdx.x >> 5;
    #pragma unroll
    for (int r = 0; r < 4; ++r) {
        const int b = bt * 32 + ty + r * 8;
        const int k = kt * 32 + tx;
        tile[ty + r * 8][tx] = x[(size_t)b * (T_ * D_) + (size_t)t * D_ + k];
    }
    __syncthreads();
    #pragma unroll
    for (int r = 0; r < 4; ++r) {
        const int k = kt * 32 + ty + r * 8;
        const int b = bt * 32 + tx;
        xT[((size_t)t * D_ + k) * B_ + b] = tile[tx][ty + r * 8];
    }
}

// ---------------- pack W: Wpk[blk256][k1024][c8]; k<512 from wk else wr ------------
__global__ __launch_bounds__(1024) void pack_w(const float* __restrict__ wk,
                                               const float* __restrict__ wr,
                                               float* __restrict__ Wpk)
{
    const size_t idx = (size_t)blockIdx.x * 1024 + threadIdx.x;
    const int    c   = (int)(idx & 7);
    const size_t k   = (idx >> 3) & 1023;
    const int    blk = (int)(idx >> 13);
    const int    col = ((c >> 1) << 9) + blk * 2 + (c & 1);
    Wpk[idx] = (k < 512) ? wk[k * G4 + col] : wr[(k - 512) * G4 + col];
}

// ---------------- zx[t][gc][b] = bias + x_t @ Wk  (stage-64; bitwise == R3) --------
__global__ __launch_bounds__(NTHR, 4) void zx_gemm(
    const float* __restrict__ xT, const float* __restrict__ Wpk,
    const float* __restrict__ bias, float* __restrict__ zx)
{
    __shared__ float parts[8][128][9];
    __shared__ float bias_l[8];
    const int tid = threadIdx.x, blk = blockIdx.x, u0 = blk * 2;
    if (tid < 8) bias_l[tid] = bias[(tid >> 1) * U_ + u0 + (tid & 1)];
    const int b = tid & 127, ksub = tid >> 7;
    const int ksub_u = __builtin_amdgcn_readfirstlane(ksub);
    const float* __restrict__ wp = Wpk + ((size_t)blk * 1024 + (size_t)ksub_u * 64) * 8;
    __syncthreads();

    for (int t = 0; t < T_; ++t) {
        const float* __restrict__ xp = xT + ((size_t)t * D_ + ksub * 64) * B_ + b;
        float xv[64];
        #pragma unroll
        for (int i = 0; i < 64; ++i) xv[i] = xp[(size_t)i * B_];   // one latency exposure
        float acc[8] = {0.f,0.f,0.f,0.f,0.f,0.f,0.f,0.f};
        #pragma unroll
        for (int kq = 0; kq < 16; ++kq) {
            const float v0 = xv[kq * 4 + 0];
            const float v1 = xv[kq * 4 + 1];
            const float v2 = xv[kq * 4 + 2];
            const float v3 = xv[kq * 4 + 3];
            const float* __restrict__ w = wp + kq * 32;            // wave-uniform -> s_load
            #pragma unroll
            for (int c = 0; c < 8; ++c)
                acc[c] += v0 * w[c] + v1 * w[8 + c] + v2 * w[16 + c] + v3 * w[24 + c];
        }
        #pragma unroll
        for (int c = 0; c < 8; ++c) parts[ksub][b][c] = acc[c];
        __syncthreads();
        {
            const int c = tid >> 7, bb = tid & 127;
            float s = bias_l[c];
            #pragma unroll
            for (int ks = 0; ks < 8; ++ks) s += parts[ks][bb][c];
            zx[((size_t)t * G4 + (c >> 1) * U_ + u0 + (c & 1)) * B_ + bb] = s;
        }
        __syncthreads();
    }
}

// ---------------- main loop v3 (fixed): z-space recurrence -------------------------
// Block owns 2 u (8 gate cols). W_r via wave-uniform s_load from Wpk (k>=512 half).
// zr state (LDS) carries hb@Wr, blended with ug_prev (= ug(t-1)) -- THE R6 FIX.
// delta: per-block pd -> 16 leader blocks aggregate to pd2 during everyone's GEMM
// window; consumers read 16 values at next step's resolve. ONE barrier per step.
// ctrl: [g*16] g<16 group ctrs, [256] root, [272] dready.
__global__ __launch_bounds__(NTHR, 4) void skiplstm_loop3(
    const float* __restrict__ zx, const float* __restrict__ Wpk,
    const float* __restrict__ dk, const float* __restrict__ dbp,
    float* __restrict__ out, float* __restrict__ hn,
    float* __restrict__ pd, float* __restrict__ pd2, unsigned* __restrict__ ctrl)
{
    __shared__ float parts[8][128][9];           // 36KB  zn = h_n @ Wr partials
    __shared__ float zxl[2][8][128];             // 8KB   zx double buffer
    __shared__ float zr[8][128];                 // 4KB   z-space carried state
    __shared__ float red[8][128];                // 4KB   leader reduce scratch
    __shared__ float h_state[128][2], c_state[128][2];
    __shared__ float ut_lds[128], ug_lds[128], ug_prev_lds[128];
    __shared__ float dk_l[4];
    __shared__ float db_l;

    const int tid = threadIdx.x;
    const int blk = blockIdx.x;
    const int u0  = blk * 2;

    // ---- init ----
    for (int i = tid; i < 9216; i += NTHR) ((float*)parts)[i] = 0.f;
    ((float*)zr)[tid & 1023] = 0.f;
    {
        const int c = tid >> 7, b = tid & 127;
        zxl[0][c][b] = zx[((size_t)0 * G4 + ((c >> 1) << 9) + u0 + (c & 1)) * B_ + b];
    }
    if (tid < 128) {
        ut_lds[tid] = 1.0f; ug_lds[tid] = 1.0f; ug_prev_lds[tid] = 1.0f;
        h_state[tid][0] = 0.f; h_state[tid][1] = 0.f;
        c_state[tid][0] = 0.f; c_state[tid][1] = 0.f;
    }
    if (tid < 2) { dk_l[tid] = dk[u0 + tid]; dk_l[2 + tid] = dk[U_ + u0 + tid]; }
    if (tid == 0) db_l = dbp[0];
    __syncthreads();

    const int bI = tid & 127, ksI = tid >> 7;
    const int ks_u = __builtin_amdgcn_readfirstlane(ksI);
    const float* __restrict__ wp = Wpk + ((size_t)blk * 1024 + 512 + (size_t)ks_u * 64) * 8;

    #pragma unroll 1
    for (int t = 0; t < T_; ++t) {
        // ---- resolve delta(t-1): ut(t), ug(t); save ug(t-1) ----
        if (t > 0) {
            if (tid == 0) {
                while (AGENT_LDA(&ctrl[272]) < (unsigned)(16 * t))
                    __builtin_amdgcn_s_sleep(1);
            }
            __syncthreads();
            if (tid < 128) {
                const float* __restrict__ p2 = pd2 + ((t - 1) & 1) * 2048;
                float ss = 0.f;
                #pragma unroll
                for (int a = 0; a < 16; ++a) ss += AGENT_LD(p2 + a * 128 + tid);
                const float dlt = sigm(ss + db_l);
                const float utp = ut_lds[tid];
                const float ugp = rintf(utp);              // ug(t-1)
                const float utn = ugp * dlt + (1.f - ugp) * (utp + fminf(dlt, 1.f - utp));
                ug_prev_lds[tid] = ugp;                    // save BEFORE overwrite
                ut_lds[tid] = utn;
                ug_lds[tid] = rintf(utn);                  // ug(t)
            }
            __syncthreads();
        }

        // ---- gates (waves 0-3) ----
        if (tid < 256) {
            const int bb = tid >> 1, j = tid & 1;
            const float ug  = ug_lds[bb];        // ug(t)   : h/c/out blends
            const float ugp = ug_prev_lds[bb];   // ug(t-1) : z-space blend (FIX)
            float z[4];
            #pragma unroll
            for (int g = 0; g < 4; ++g) {
                const int c = g * 2 + j;
                float zn = parts[0][bb][c];
                #pragma unroll
                for (int ks = 1; ks < 8; ++ks) zn += parts[ks][bb][c];
                const float zrn = ugp * zr[c][bb] + (1.f - ugp) * zn;  // exact select
                zr[c][bb] = zrn;
                z[g] = zxl[t & 1][c][bb] + zrn;
            }
            const float c_old = c_state[bb][j];
            const float si = sigm(z[0]);
            const float sf = sigm(z[1]);
            const float gt = tanhf(z[2]);
            const float so = sigm(z[3]);
            const float c_n = sf * c_old + si * gt;
            const float h_n = so * tanhf(c_n);
            const float h_old = h_state[bb][j];
            const float hbv = ug * h_old + (1.f - ug) * h_n;
            const float cbv = ug * c_old + (1.f - ug) * c_n;
            out[(size_t)bb * (T_ * U_) + (size_t)t * U_ + u0 + j] = h_n;
            AGENT_ST(hn + (t & 1) * (U_ * B_) + (size_t)(u0 + j) * B_ + bb, h_n); // candidate
            h_state[bb][j] = hbv;
            c_state[bb][j] = cbv;
            float p = hbv * dk_l[j] + cbv * dk_l[2 + j];
            p += __shfl_xor(p, 1);
            if (j == 0) AGENT_ST(pd + (t & 1) * (NBLK * B_) + blk * B_ + bb, p);
        }
        __syncthreads();           // LDS hazards + drain stores before arrive

        if (t == T_ - 1) break;

        // ---- single hierarchical barrier ----
        if (tid == 0) {
            const unsigned old = __hip_atomic_fetch_add(&ctrl[(blk >> 4) * 16], 1u,
                                    __ATOMIC_RELEASE, __HIP_MEMORY_SCOPE_AGENT);
            if (old + 1u == (unsigned)(16 * (t + 1)))
                __hip_atomic_fetch_add(&ctrl[256], 1u,
                                    __ATOMIC_RELEASE, __HIP_MEMORY_SCOPE_AGENT);
            while (AGENT_LDA(&ctrl[256]) < (unsigned)(16 * (t + 1)))
                __builtin_amdgcn_s_sleep(1);
        }
        __syncthreads();

        // ---- leaders aggregate pd(t) -> pd2 (overlaps everyone's GEMM) ----
        if (blk < 16) {
            const float* __restrict__ pdt = pd + (t & 1) * (NBLK * B_);
            const int i = tid >> 7, r = tid & 127;
            red[i][r] = AGENT_LD(pdt + (size_t)(blk * 16 + i) * B_ + r)
                      + AGENT_LD(pdt + (size_t)(blk * 16 + i + 8) * B_ + r);
            __syncthreads();
            if (tid < 128) {
                float ss = red[0][tid];
                #pragma unroll
                for (int i2 = 1; i2 < 8; ++i2) ss += red[i2][tid];
                AGENT_ST(pd2 + (t & 1) * 2048 + blk * 128 + tid, ss);
            }
            __syncthreads();
            if (tid == 0)
                __hip_atomic_fetch_add(&ctrl[272], 1u,
                                    __ATOMIC_RELEASE, __HIP_MEMORY_SCOPE_AGENT);
        }

        // ---- GEMM: zn = h_n(t) @ Wr (W via s_load); zx(t+1) prefetch ----
        {
            const float zreg = zx[((size_t)(t + 1) * G4 + ((ksI >> 1) << 9) + u0 + (ksI & 1)) * B_ + bI];
            const float* __restrict__ hp = hn + (t & 1) * (U_ * B_) + (size_t)(ksI * 64) * B_ + bI;
            float hv[64];
            #pragma unroll
            for (int i = 0; i < 64; ++i) hv[i] = AGENT_LD(hp + (size_t)i * B_);  // one exposure
            float acc[8] = {0.f,0.f,0.f,0.f,0.f,0.f,0.f,0.f};
            #pragma unroll
            for (int kq = 0; kq < 16; ++kq) {
                const float v0 = hv[kq * 4 + 0];
                const float v1 = hv[kq * 4 + 1];
                const float v2 = hv[kq * 4 + 2];
                const float v3 = hv[kq * 4 + 3];
                const float* __restrict__ w = wp + kq * 32;        // wave-uniform -> s_load
                #pragma unroll
                for (int c = 0; c < 8; ++c)
                    acc[c] += v0 * w[c] + v1 * w[8 + c] + v2 * w[16 + c] + v3 * w[24 + c];
            }
            #pragma unroll
            for (int c = 0; c < 8; ++c) parts[ksI][bI][c] = acc[c];
            zxl[(t + 1) & 1][ksI][bI] = zreg;
        }
        __syncthreads();           // parts/zxl ready for gates(t+1)
    }
}

// ---------------- R2 fallback (ws too small): proven 55 ms path --------------------
__global__ __launch_bounds__(NTHR, 4) void skiplstm_kernel_T(
    const float* __restrict__ xT, const float* __restrict__ wk,
    const float* __restrict__ wr, const float* __restrict__ bias,
    const float* __restrict__ dk, const float* __restrict__ dbp,
    float* __restrict__ out, float* __restrict__ hbuf, float* __restrict__ pd)
{
    __shared__ __align__(16) float Wlds[8][1024];
    __shared__ float parts[8][128][9];
    __shared__ float c_state[128][2];
    __shared__ float ut_lds[128];
    __shared__ float bias_l[8];
    __shared__ float dk_l[4];
    __shared__ float db_l;

    const int tid = threadIdx.x;
    const int u0 = blockIdx.x * 2;

    #pragma unroll
    for (int c = 0; c < 8; ++c) {
        const int g = c >> 1, j = c & 1;
        const int gcol = g * U_ + u0 + j;
        Wlds[c][tid] = (tid < D_) ? wk[(size_t)tid * G4 + gcol]
                                  : wr[(size_t)(tid - D_) * G4 + gcol];
    }
    if (tid < 8)  bias_l[tid] = bias[(tid >> 1) * U_ + u0 + (tid & 1)];
    if (tid < 2) { dk_l[tid] = dk[u0 + tid]; dk_l[2 + tid] = dk[U_ + u0 + tid]; }
    if (tid == 0) db_l = dbp[0];
    if (tid < 128) { ut_lds[tid] = 1.0f; c_state[tid][0] = 0.0f; c_state[tid][1] = 0.0f; }
    if (tid < 512) hbuf[blockIdx.x * 512 + tid] = 0.0f;

    cg::grid_group grid = cg::this_grid();
    __syncthreads();
    grid.sync();

    const int b    = tid & 127;
    const int ksub = tid >> 7;

    #pragma unroll 1
    for (int t = 0; t < T_; ++t) {
        const float* __restrict__ hcurT = hbuf + (t & 1) * (U_ * B_);
        float* __restrict__ hnxtT = hbuf + ((t + 1) & 1) * (U_ * B_);

        const float* __restrict__ src = (ksub < 4)
            ? (xT + ((size_t)t * D_ + ksub * 128) * B_ + b)
            : (hcurT + (size_t)(ksub - 4) * 128 * B_ + b);

        float acc[8] = {0.f,0.f,0.f,0.f,0.f,0.f,0.f,0.f};
        #pragma unroll 2
        for (int kq = 0; kq < 32; ++kq) {
            const float v0 = src[(kq * 4 + 0) * B_];
            const float v1 = src[(kq * 4 + 1) * B_];
            const float v2 = src[(kq * 4 + 2) * B_];
            const float v3 = src[(kq * 4 + 3) * B_];
            const int k4 = ksub * 32 + kq;
            #pragma unroll
            for (int c = 0; c < 8; ++c) {
                const float4 w = ((const float4*)(&Wlds[c][0]))[k4];
                acc[c] += v0 * w.x + v1 * w.y + v2 * w.z + v3 * w.w;
            }
        }
        #pragma unroll
        for (int c = 0; c < 8; ++c) parts[ksub][b][c] = acc[c];
        __syncthreads();

        if (tid < 256) {
            const int bb = tid >> 1, j = tid & 1;
            float z[4];
            #pragma unroll
            for (int g = 0; g < 4; ++g) {
                float s = bias_l[g*2 + j];
                #pragma unroll
                for (int ks = 0; ks < 8; ++ks) s += parts[ks][bb][g*2 + j];
                z[g] = s;
            }
            const float ut    = ut_lds[bb];
            const float ug    = rintf(ut);
            const float c_old = c_state[bb][j];
            const float si = sigm(z[0]);
            const float sf = sigm(z[1]);
            const float gg = tanhf(z[2]);
            const float so = sigm(z[3]);
            const float c_n = sf * c_old + si * gg;
            const float h_n = so * tanhf(c_n);
            const float h_old = hcurT[(u0 + j) * B_ + bb];
            const float hbv = ug * h_old + (1.f - ug) * h_n;
            const float cbv = ug * c_old + (1.f - ug) * c_n;
            out[(size_t)bb * (T_ * U_) + (size_t)t * U_ + u0 + j] = h_n;
            hnxtT[(u0 + j) * B_ + bb] = hbv;
            c_state[bb][j] = cbv;
            float p = hbv * dk_l[j] + cbv * dk_l[2 + j];
            p += __shfl_xor(p, 1);
            if (j == 0) pd[(t & 1) * (NBLK * B_) + blockIdx.x * B_ + bb] = p;
        }

        grid.sync();

        {
            const int bb2 = tid >> 3, o = tid & 7;
            const float* __restrict__ pdt = pd + (t & 1) * (NBLK * B_);
            float s = 0.f;
            #pragma unroll 1
            for (int i = 0; i < 32; ++i) s += pdt[(o * 32 + i) * B_ + bb2];
            s += __shfl_xor(s, 1);
            s += __shfl_xor(s, 2);
            s += __shfl_xor(s, 4);
            if (o == 0) {
                const float delta = sigm(s + db_l);
                const float ut = ut_lds[bb2];
                const float ug = rintf(ut);
                ut_lds[bb2] = ug * delta + (1.f - ug) * (ut + fminf(delta, 1.f - ut));
            }
        }
        __syncthreads();
    }
}

// ---------------- host -------------------------------------------------------------
extern "C" void kernel_launch(void* const* d_in, const int* in_sizes, int n_in,
                              void* d_out, int out_size, void* d_ws, size_t ws_size,
                              hipStream_t stream)
{
    (void)in_sizes; (void)n_in; (void)out_size;
    const float* x  = (const float*)d_in[0];
    const float* wk = (const float*)d_in[1];
    const float* wr = (const float*)d_in[2];
    const float* bs = (const float*)d_in[3];
    const float* dk = (const float*)d_in[4];
    const float* db = (const float*)d_in[5];
    float* out = (float*)d_out;

    const size_t zx_b   = (size_t)T_ * G4 * B_ * 4;          // 1 GiB
    const size_t xT_b   = (size_t)T_ * D_ * B_ * 4;          // 256 MiB
    const size_t wpk_b  = (size_t)NBLK * 1024 * 8 * 4;       // 8 MiB
    const size_t hn_b   = (size_t)2 * U_ * B_ * 4;           // 512 KiB
    const size_t pd_b   = (size_t)2 * NBLK * B_ * 4;         // 256 KiB
    const size_t pd2_b  = (size_t)2 * 16 * 128 * 4;          // 16 KiB
    const size_t ctrl_b = 4096;
    const size_t tail_b = hn_b + pd_b + pd2_b + ctrl_b;
    const size_t need   = zx_b + xT_b + wpk_b + tail_b;

    char* w = (char*)d_ws;

    if (ws_size >= need) {
        float* zxp  = (float*)w;
        float* xT   = (float*)(w + zx_b);
        float* Wpk  = (float*)(w + zx_b + xT_b);
        float* hn   = (float*)(w + zx_b + xT_b + wpk_b);
        float* pd   = (float*)(w + zx_b + xT_b + wpk_b + hn_b);
        float* pd2  = (float*)(w + zx_b + xT_b + wpk_b + hn_b + pd_b);
        unsigned* ctrl = (unsigned*)(w + zx_b + xT_b + wpk_b + hn_b + pd_b + pd2_b);

        hipMemsetAsync(hn, 0, tail_b, stream);
        transpose_x<<<dim3(T_ * 16 * 4), dim3(256), 0, stream>>>(x, xT);
        pack_w<<<dim3(2048), dim3(1024), 0, stream>>>(wk, wr, Wpk);
        zx_gemm<<<dim3(NBLK), dim3(NTHR), 0, stream>>>(xT, Wpk, bs, zxp);

        void* args[] = { (void*)&zxp, (void*)&Wpk, (void*)&dk, (void*)&db,
                         (void*)&out, (void*)&hn, (void*)&pd, (void*)&pd2, (void*)&ctrl };
        hipLaunchCooperativeKernel(reinterpret_cast<void*>(skiplstm_loop3),
                                   dim3(NBLK), dim3(NTHR), args, 0, stream);
    } else {
        float* xT   = (float*)d_ws;
        float* hbuf = xT + (size_t)T_ * D_ * B_;
        float* pd   = hbuf + 2 * U_ * B_;
        transpose_x<<<dim3(T_ * 16 * 4), dim3(256), 0, stream>>>(x, xT);
        void* args[] = { (void*)&xT, (void*)&wk, (void*)&wr, (void*)&bs, (void*)&dk, (void*)&db,
                         (void*)&out, (void*)&hbuf, (void*)&pd };
        hipLaunchCooperativeKernel(reinterpret_cast<void*>(skiplstm_kernel_T),
                                   dim3(NBLK), dim3(NTHR), args, 0, stream);
    }
}

// Round 8
// 44883.011 us; speedup vs baseline: 1.2102x; 1.2102x over previous
//
#include <hip/hip_runtime.h>
#include <hip/hip_fp16.h>
#include <hip/hip_cooperative_groups.h>

namespace cg = cooperative_groups;

constexpr int B_ = 128, T_ = 1024, D_ = 512, U_ = 512;
constexpr int NBLK = 256, NTHR = 1024;
constexpr int G4 = 4 * U_;   // 2048 gate columns

__device__ __forceinline__ float sigm(float v) { return 1.0f / (1.0f + expf(-v)); }

#define AGENT_LD(p)    __hip_atomic_load((p), __ATOMIC_RELAXED, __HIP_MEMORY_SCOPE_AGENT)
#define AGENT_LDA(p)   __hip_atomic_load((p), __ATOMIC_ACQUIRE, __HIP_MEMORY_SCOPE_AGENT)
#define AGENT_ST(p, v) __hip_atomic_store((p), (v), __ATOMIC_RELAXED, __HIP_MEMORY_SCOPE_AGENT)

template <typename ZT> __device__ __forceinline__ ZT    to_zt(float v);
template <> __device__ __forceinline__ float  to_zt<float>(float v)  { return v; }
template <> __device__ __forceinline__ __half to_zt<__half>(float v) { return __float2half(v); }
__device__ __forceinline__ float from_zt(float v)  { return v; }
__device__ __forceinline__ float from_zt(__half v) { return __half2float(v); }

// ---------------- x[b][t][k] -> xT[t][k][b] ----------------------------------------
__global__ __launch_bounds__(256) void transpose_x(const float* __restrict__ x,
                                                   float* __restrict__ xT)
{
    __shared__ float tile[32][33];
    const int tileId = blockIdx.x;
    const int bt = tileId & 3;
    const int kt = (tileId >> 2) & 15;
    const int t  = tileId >> 6;
    const int tx = threadIdx.x & 31;
    const int ty = threadIdx.x >> 5;
    #pragma unroll
    for (int r = 0; r < 4; ++r) {
        const int b = bt * 32 + ty + r * 8;
        const int k = kt * 32 + tx;
        tile[ty + r * 8][tx] = x[(size_t)b * (T_ * D_) + (size_t)t * D_ + k];
    }
    __syncthreads();
    #pragma unroll
    for (int r = 0; r < 4; ++r) {
        const int k = kt * 32 + ty + r * 8;
        const int b = bt * 32 + tx;
        xT[((size_t)t * D_ + k) * B_ + b] = tile[tx][ty + r * 8];
    }
}

// ---------------- pack W: Wpk[blk256][k1024][c8]; k<512 from wk else wr ------------
__global__ __launch_bounds__(1024) void pack_w(const float* __restrict__ wk,
                                               const float* __restrict__ wr,
                                               float* __restrict__ Wpk)
{
    const size_t idx = (size_t)blockIdx.x * 1024 + threadIdx.x;
    const int    c   = (int)(idx & 7);
    const size_t k   = (idx >> 3) & 1023;
    const int    blk = (int)(idx >> 13);
    const int    col = ((c >> 1) << 9) + blk * 2 + (c & 1);
    Wpk[idx] = (k < 512) ? wk[k * G4 + col] : wr[(k - 512) * G4 + col];
}

// ---------------- zx[t][gc][b] = bias + x_t @ Wk  (stage-64) -----------------------
template <typename ZT>
__global__ __launch_bounds__(NTHR, 4) void zx_gemm(
    const float* __restrict__ xT, const float* __restrict__ Wpk,
    const float* __restrict__ bias, ZT* __restrict__ zx)
{
    __shared__ float parts[8][128][9];
    __shared__ float bias_l[8];
    const int tid = threadIdx.x, blk = blockIdx.x, u0 = blk * 2;
    if (tid < 8) bias_l[tid] = bias[(tid >> 1) * U_ + u0 + (tid & 1)];
    const int b = tid & 127, ksub = tid >> 7;
    const int ksub_u = __builtin_amdgcn_readfirstlane(ksub);
    const float* __restrict__ wp = Wpk + ((size_t)blk * 1024 + (size_t)ksub_u * 64) * 8;
    __syncthreads();

    for (int t = 0; t < T_; ++t) {
        const float* __restrict__ xp = xT + ((size_t)t * D_ + ksub * 64) * B_ + b;
        float xv[64];
        #pragma unroll
        for (int i = 0; i < 64; ++i) xv[i] = xp[(size_t)i * B_];   // one latency exposure
        float acc[8] = {0.f,0.f,0.f,0.f,0.f,0.f,0.f,0.f};
        #pragma unroll
        for (int kq = 0; kq < 16; ++kq) {
            const float v0 = xv[kq * 4 + 0];
            const float v1 = xv[kq * 4 + 1];
            const float v2 = xv[kq * 4 + 2];
            const float v3 = xv[kq * 4 + 3];
            const float* __restrict__ w = wp + kq * 32;            // wave-uniform -> s_load
            #pragma unroll
            for (int c = 0; c < 8; ++c)
                acc[c] += v0 * w[c] + v1 * w[8 + c] + v2 * w[16 + c] + v3 * w[24 + c];
        }
        #pragma unroll
        for (int c = 0; c < 8; ++c) parts[ksub][b][c] = acc[c];
        __syncthreads();
        {
            const int c = tid >> 7, bb = tid & 127;
            float s = bias_l[c];
            #pragma unroll
            for (int ks = 0; ks < 8; ++ks) s += parts[ks][bb][c];
            zx[((size_t)t * G4 + (c >> 1) * U_ + u0 + (c & 1)) * B_ + bb] = to_zt<ZT>(s);
        }
        __syncthreads();
    }
}

// ---------------- main loop v3: z-space recurrence ---------------------------------
// Block owns 2 u (8 gate cols). W_r via wave-uniform s_load from Wpk (k>=512 half).
// zr state (LDS) carries hb@Wr, blended with ug_prev (= ug(t-1)).
// delta: per-block pd -> 16 leader blocks aggregate to pd2 during everyone's GEMM
// window; consumers read 16 values at next step's resolve. ONE barrier per step.
// ctrl: [g*16] g<16 group ctrs, [256] root, [272] dready.
template <typename ZT>
__global__ __launch_bounds__(NTHR, 4) void skiplstm_loop3(
    const ZT* __restrict__ zx, const float* __restrict__ Wpk,
    const float* __restrict__ dk, const float* __restrict__ dbp,
    float* __restrict__ out, float* __restrict__ hn,
    float* __restrict__ pd, float* __restrict__ pd2, unsigned* __restrict__ ctrl)
{
    __shared__ float parts[8][128][9];           // 36KB  zn = h_n @ Wr partials
    __shared__ float zxl[2][8][128];             // 8KB   zx double buffer
    __shared__ float zr[8][128];                 // 4KB   z-space carried state
    __shared__ float red[8][128];                // 4KB   leader reduce scratch
    __shared__ float h_state[128][2], c_state[128][2];
    __shared__ float ut_lds[128], ug_lds[128], ug_prev_lds[128];
    __shared__ float dk_l[4];
    __shared__ float db_l;

    const int tid = threadIdx.x;
    const int blk = blockIdx.x;
    const int u0  = blk * 2;

    // ---- init ----
    for (int i = tid; i < 9216; i += NTHR) ((float*)parts)[i] = 0.f;
    ((float*)zr)[tid & 1023] = 0.f;
    {
        const int c = tid >> 7, b = tid & 127;
        zxl[0][c][b] = from_zt(zx[((size_t)0 * G4 + ((c >> 1) << 9) + u0 + (c & 1)) * B_ + b]);
    }
    if (tid < 128) {
        ut_lds[tid] = 1.0f; ug_lds[tid] = 1.0f; ug_prev_lds[tid] = 1.0f;
        h_state[tid][0] = 0.f; h_state[tid][1] = 0.f;
        c_state[tid][0] = 0.f; c_state[tid][1] = 0.f;
    }
    if (tid < 2) { dk_l[tid] = dk[u0 + tid]; dk_l[2 + tid] = dk[U_ + u0 + tid]; }
    if (tid == 0) db_l = dbp[0];
    __syncthreads();

    const int bI = tid & 127, ksI = tid >> 7;
    const int ks_u = __builtin_amdgcn_readfirstlane(ksI);
    const float* __restrict__ wp = Wpk + ((size_t)blk * 1024 + 512 + (size_t)ks_u * 64) * 8;

    #pragma unroll 1
    for (int t = 0; t < T_; ++t) {
        // ---- resolve delta(t-1): ut(t), ug(t); save ug(t-1) ----
        if (t > 0) {
            if (tid == 0) {
                while (AGENT_LDA(&ctrl[272]) < (unsigned)(16 * t))
                    __builtin_amdgcn_s_sleep(1);
            }
            __syncthreads();
            if (tid < 128) {
                const float* __restrict__ p2 = pd2 + ((t - 1) & 1) * 2048;
                float ss = 0.f;
                #pragma unroll
                for (int a = 0; a < 16; ++a) ss += AGENT_LD(p2 + a * 128 + tid);
                const float dlt = sigm(ss + db_l);
                const float utp = ut_lds[tid];
                const float ugp = rintf(utp);              // ug(t-1)
                const float utn = ugp * dlt + (1.f - ugp) * (utp + fminf(dlt, 1.f - utp));
                ug_prev_lds[tid] = ugp;                    // save BEFORE overwrite
                ut_lds[tid] = utn;
                ug_lds[tid] = rintf(utn);                  // ug(t)
            }
            __syncthreads();
        }

        // ---- gates (waves 0-3) ----
        if (tid < 256) {
            const int bb = tid >> 1, j = tid & 1;
            const float ug  = ug_lds[bb];        // ug(t)   : h/c/out blends
            const float ugp = ug_prev_lds[bb];   // ug(t-1) : z-space blend
            float z[4];
            #pragma unroll
            for (int g = 0; g < 4; ++g) {
                const int c = g * 2 + j;
                float zn = parts[0][bb][c];
                #pragma unroll
                for (int ks = 1; ks < 8; ++ks) zn += parts[ks][bb][c];
                const float zrn = ugp * zr[c][bb] + (1.f - ugp) * zn;  // exact select
                zr[c][bb] = zrn;
                z[g] = zxl[t & 1][c][bb] + zrn;
            }
            const float c_old = c_state[bb][j];
            const float si = sigm(z[0]);
            const float sf = sigm(z[1]);
            const float gt = tanhf(z[2]);
            const float so = sigm(z[3]);
            const float c_n = sf * c_old + si * gt;
            const float h_n = so * tanhf(c_n);
            const float h_old = h_state[bb][j];
            const float hbv = ug * h_old + (1.f - ug) * h_n;
            const float cbv = ug * c_old + (1.f - ug) * c_n;
            out[(size_t)bb * (T_ * U_) + (size_t)t * U_ + u0 + j] = h_n;
            AGENT_ST(hn + (t & 1) * (U_ * B_) + (size_t)(u0 + j) * B_ + bb, h_n); // candidate
            h_state[bb][j] = hbv;
            c_state[bb][j] = cbv;
            float p = hbv * dk_l[j] + cbv * dk_l[2 + j];
            p += __shfl_xor(p, 1);
            if (j == 0) AGENT_ST(pd + (t & 1) * (NBLK * B_) + blk * B_ + bb, p);
        }
        __syncthreads();           // LDS hazards + drain stores before arrive

        if (t == T_ - 1) break;

        // ---- single hierarchical barrier ----
        if (tid == 0) {
            const unsigned old = __hip_atomic_fetch_add(&ctrl[(blk >> 4) * 16], 1u,
                                    __ATOMIC_RELEASE, __HIP_MEMORY_SCOPE_AGENT);
            if (old + 1u == (unsigned)(16 * (t + 1)))
                __hip_atomic_fetch_add(&ctrl[256], 1u,
                                    __ATOMIC_RELEASE, __HIP_MEMORY_SCOPE_AGENT);
            while (AGENT_LDA(&ctrl[256]) < (unsigned)(16 * (t + 1)))
                __builtin_amdgcn_s_sleep(1);
        }
        __syncthreads();

        // ---- leaders aggregate pd(t) -> pd2 (overlaps everyone's GEMM) ----
        if (blk < 16) {
            const float* __restrict__ pdt = pd + (t & 1) * (NBLK * B_);
            const int i = tid >> 7, r = tid & 127;
            red[i][r] = AGENT_LD(pdt + (size_t)(blk * 16 + i) * B_ + r)
                      + AGENT_LD(pdt + (size_t)(blk * 16 + i + 8) * B_ + r);
            __syncthreads();
            if (tid < 128) {
                float ss = red[0][tid];
                #pragma unroll
                for (int i2 = 1; i2 < 8; ++i2) ss += red[i2][tid];
                AGENT_ST(pd2 + (t & 1) * 2048 + blk * 128 + tid, ss);
            }
            __syncthreads();
            if (tid == 0)
                __hip_atomic_fetch_add(&ctrl[272], 1u,
                                    __ATOMIC_RELEASE, __HIP_MEMORY_SCOPE_AGENT);
        }

        // ---- GEMM: zn = h_n(t) @ Wr (W via s_load); zx(t+1) prefetch ----
        {
            const ZT zreg = zx[((size_t)(t + 1) * G4 + ((ksI >> 1) << 9) + u0 + (ksI & 1)) * B_ + bI];
            const float* __restrict__ hp = hn + (t & 1) * (U_ * B_) + (size_t)(ksI * 64) * B_ + bI;
            float hv[64];
            #pragma unroll
            for (int i = 0; i < 64; ++i) hv[i] = AGENT_LD(hp + (size_t)i * B_);  // one exposure
            float acc[8] = {0.f,0.f,0.f,0.f,0.f,0.f,0.f,0.f};
            #pragma unroll
            for (int kq = 0; kq < 16; ++kq) {
                const float v0 = hv[kq * 4 + 0];
                const float v1 = hv[kq * 4 + 1];
                const float v2 = hv[kq * 4 + 2];
                const float v3 = hv[kq * 4 + 3];
                const float* __restrict__ w = wp + kq * 32;        // wave-uniform -> s_load
                #pragma unroll
                for (int c = 0; c < 8; ++c)
                    acc[c] += v0 * w[c] + v1 * w[8 + c] + v2 * w[16 + c] + v3 * w[24 + c];
            }
            #pragma unroll
            for (int c = 0; c < 8; ++c) parts[ksI][bI][c] = acc[c];
            zxl[(t + 1) & 1][ksI][bI] = from_zt(zreg);
        }
        __syncthreads();           // parts/zxl ready for gates(t+1)
    }
}

// ---------------- R2 fallback (ws too small): proven 55 ms path --------------------
__global__ __launch_bounds__(NTHR, 4) void skiplstm_kernel_T(
    const float* __restrict__ xT, const float* __restrict__ wk,
    const float* __restrict__ wr, const float* __restrict__ bias,
    const float* __restrict__ dk, const float* __restrict__ dbp,
    float* __restrict__ out, float* __restrict__ hbuf, float* __restrict__ pd)
{
    __shared__ __align__(16) float Wlds[8][1024];
    __shared__ float parts[8][128][9];
    __shared__ float c_state[128][2];
    __shared__ float ut_lds[128];
    __shared__ float bias_l[8];
    __shared__ float dk_l[4];
    __shared__ float db_l;

    const int tid = threadIdx.x;
    const int u0 = blockIdx.x * 2;

    #pragma unroll
    for (int c = 0; c < 8; ++c) {
        const int g = c >> 1, j = c & 1;
        const int gcol = g * U_ + u0 + j;
        Wlds[c][tid] = (tid < D_) ? wk[(size_t)tid * G4 + gcol]
                                  : wr[(size_t)(tid - D_) * G4 + gcol];
    }
    if (tid < 8)  bias_l[tid] = bias[(tid >> 1) * U_ + u0 + (tid & 1)];
    if (tid < 2) { dk_l[tid] = dk[u0 + tid]; dk_l[2 + tid] = dk[U_ + u0 + tid]; }
    if (tid == 0) db_l = dbp[0];
    if (tid < 128) { ut_lds[tid] = 1.0f; c_state[tid][0] = 0.0f; c_state[tid][1] = 0.0f; }
    if (tid < 512) hbuf[blockIdx.x * 512 + tid] = 0.0f;

    cg::grid_group grid = cg::this_grid();
    __syncthreads();
    grid.sync();

    const int b    = tid & 127;
    const int ksub = tid >> 7;

    #pragma unroll 1
    for (int t = 0; t < T_; ++t) {
        const float* __restrict__ hcurT = hbuf + (t & 1) * (U_ * B_);
        float* __restrict__ hnxtT = hbuf + ((t + 1) & 1) * (U_ * B_);

        const float* __restrict__ src = (ksub < 4)
            ? (xT + ((size_t)t * D_ + ksub * 128) * B_ + b)
            : (hcurT + (size_t)(ksub - 4) * 128 * B_ + b);

        float acc[8] = {0.f,0.f,0.f,0.f,0.f,0.f,0.f,0.f};
        #pragma unroll 2
        for (int kq = 0; kq < 32; ++kq) {
            const float v0 = src[(kq * 4 + 0) * B_];
            const float v1 = src[(kq * 4 + 1) * B_];
            const float v2 = src[(kq * 4 + 2) * B_];
            const float v3 = src[(kq * 4 + 3) * B_];
            const int k4 = ksub * 32 + kq;
            #pragma unroll
            for (int c = 0; c < 8; ++c) {
                const float4 w = ((const float4*)(&Wlds[c][0]))[k4];
                acc[c] += v0 * w.x + v1 * w.y + v2 * w.z + v3 * w.w;
            }
        }
        #pragma unroll
        for (int c = 0; c < 8; ++c) parts[ksub][b][c] = acc[c];
        __syncthreads();

        if (tid < 256) {
            const int bb = tid >> 1, j = tid & 1;
            float z[4];
            #pragma unroll
            for (int g = 0; g < 4; ++g) {
                float s = bias_l[g*2 + j];
                #pragma unroll
                for (int ks = 0; ks < 8; ++ks) s += parts[ks][bb][g*2 + j];
                z[g] = s;
            }
            const float ut    = ut_lds[bb];
            const float ug    = rintf(ut);
            const float c_old = c_state[bb][j];
            const float si = sigm(z[0]);
            const float sf = sigm(z[1]);
            const float gg = tanhf(z[2]);
            const float so = sigm(z[3]);
            const float c_n = sf * c_old + si * gg;
            const float h_n = so * tanhf(c_n);
            const float h_old = hcurT[(u0 + j) * B_ + bb];
            const float hbv = ug * h_old + (1.f - ug) * h_n;
            const float cbv = ug * c_old + (1.f - ug) * c_n;
            out[(size_t)bb * (T_ * U_) + (size_t)t * U_ + u0 + j] = h_n;
            hnxtT[(u0 + j) * B_ + bb] = hbv;
            c_state[bb][j] = cbv;
            float p = hbv * dk_l[j] + cbv * dk_l[2 + j];
            p += __shfl_xor(p, 1);
            if (j == 0) pd[(t & 1) * (NBLK * B_) + blockIdx.x * B_ + bb] = p;
        }

        grid.sync();

        {
            const int bb2 = tid >> 3, o = tid & 7;
            const float* __restrict__ pdt = pd + (t & 1) * (NBLK * B_);
            float s = 0.f;
            #pragma unroll 1
            for (int i = 0; i < 32; ++i) s += pdt[(o * 32 + i) * B_ + bb2];
            s += __shfl_xor(s, 1);
            s += __shfl_xor(s, 2);
            s += __shfl_xor(s, 4);
            if (o == 0) {
                const float delta = sigm(s + db_l);
                const float ut = ut_lds[bb2];
                const float ug = rintf(ut);
                ut_lds[bb2] = ug * delta + (1.f - ug) * (ut + fminf(delta, 1.f - ut));
            }
        }
        __syncthreads();
    }
}

// ---------------- host -------------------------------------------------------------
extern "C" void kernel_launch(void* const* d_in, const int* in_sizes, int n_in,
                              void* d_out, int out_size, void* d_ws, size_t ws_size,
                              hipStream_t stream)
{
    (void)in_sizes; (void)n_in; (void)out_size;
    const float* x  = (const float*)d_in[0];
    const float* wk = (const float*)d_in[1];
    const float* wr = (const float*)d_in[2];
    const float* bs = (const float*)d_in[3];
    const float* dk = (const float*)d_in[4];
    const float* db = (const float*)d_in[5];
    float* out = (float*)d_out;

    const size_t xT_b   = (size_t)T_ * D_ * B_ * 4;          // 256 MiB
    const size_t wpk_b  = (size_t)NBLK * 1024 * 8 * 4;       // 8 MiB
    const size_t hn_b   = (size_t)2 * U_ * B_ * 4;           // 512 KiB
    const size_t pd_b   = (size_t)2 * NBLK * B_ * 4;         // 256 KiB
    const size_t pd2_b  = (size_t)2 * 16 * 128 * 4;          // 16 KiB
    const size_t ctrl_b = 4096;
    const size_t zx32_b = (size_t)T_ * G4 * B_ * 4;          // 1 GiB
    const size_t zx16_b = zx32_b / 2;                        // 512 MiB
    const size_t tail_b = hn_b + pd_b + pd2_b + ctrl_b;

    const size_t need_A = zx32_b + xT_b + wpk_b + tail_b;    // ~1.26 GiB
    const size_t need_B = zx16_b + xT_b + wpk_b + tail_b;    // ~0.76 GiB

    char* w = (char*)d_ws;

    if (ws_size >= need_B) {
        const bool f32zx = (ws_size >= need_A);
        const size_t zx_b = f32zx ? zx32_b : zx16_b;
        char*  zxp  = w;
        float* xT   = (float*)(w + zx_b);
        float* Wpk  = (float*)(w + zx_b + xT_b);
        float* hn   = (float*)(w + zx_b + xT_b + wpk_b);
        float* pd   = (float*)(w + zx_b + xT_b + wpk_b + hn_b);
        float* pd2  = (float*)(w + zx_b + xT_b + wpk_b + hn_b + pd_b);
        unsigned* ctrl = (unsigned*)(w + zx_b + xT_b + wpk_b + hn_b + pd_b + pd2_b);

        hipMemsetAsync(hn, 0, tail_b, stream);
        transpose_x<<<dim3(T_ * 16 * 4), dim3(256), 0, stream>>>(x, xT);
        pack_w<<<dim3(2048), dim3(1024), 0, stream>>>(wk, wr, Wpk);

        if (f32zx) {
            float* zx = (float*)zxp;
            zx_gemm<float><<<dim3(NBLK), dim3(NTHR), 0, stream>>>(xT, Wpk, bs, zx);
            void* args[] = { (void*)&zx, (void*)&Wpk, (void*)&dk, (void*)&db,
                             (void*)&out, (void*)&hn, (void*)&pd, (void*)&pd2, (void*)&ctrl };
            hipLaunchCooperativeKernel(reinterpret_cast<void*>(skiplstm_loop3<float>),
                                       dim3(NBLK), dim3(NTHR), args, 0, stream);
        } else {
            __half* zx = (__half*)zxp;
            zx_gemm<__half><<<dim3(NBLK), dim3(NTHR), 0, stream>>>(xT, Wpk, bs, zx);
            void* args[] = { (void*)&zx, (void*)&Wpk, (void*)&dk, (void*)&db,
                             (void*)&out, (void*)&hn, (void*)&pd, (void*)&pd2, (void*)&ctrl };
            hipLaunchCooperativeKernel(reinterpret_cast<void*>(skiplstm_loop3<__half>),
                                       dim3(NBLK), dim3(NTHR), args, 0, stream);
        }
    } else {
        float* xT   = (float*)d_ws;
        float* hbuf = xT + (size_t)T_ * D_ * B_;
        float* pd   = hbuf + 2 * U_ * B_;
        transpose_x<<<dim3(T_ * 16 * 4), dim3(256), 0, stream>>>(x, xT);
        void* args[] = { (void*)&xT, (void*)&wk, (void*)&wr, (void*)&bs, (void*)&dk, (void*)&db,
                         (void*)&out, (void*)&hbuf, (void*)&pd };
        hipLaunchCooperativeKernel(reinterpret_cast<void*>(skiplstm_kernel_T),
                                   dim3(NBLK), dim3(NTHR), args, 0, stream);
    }
}

// Round 9
// 35130.331 us; speedup vs baseline: 1.5462x; 1.2776x over previous
//
#include <hip/hip_runtime.h>
#include <hip/hip_fp16.h>
#include <hip/hip_cooperative_groups.h>

namespace cg = cooperative_groups;

constexpr int B_ = 128, T_ = 1024, D_ = 512, U_ = 512;
constexpr int NBLK = 256, NTHR = 1024;
constexpr int G4 = 4 * U_;   // 2048 gate columns

__device__ __forceinline__ float sigm(float v) { return 1.0f / (1.0f + expf(-v)); }

#define AGENT_LD(p)    __hip_atomic_load((p), __ATOMIC_RELAXED, __HIP_MEMORY_SCOPE_AGENT)
#define AGENT_LDA(p)   __hip_atomic_load((p), __ATOMIC_ACQUIRE, __HIP_MEMORY_SCOPE_AGENT)
#define AGENT_ST(p, v) __hip_atomic_store((p), (v), __ATOMIC_RELAXED, __HIP_MEMORY_SCOPE_AGENT)

template <typename ZT> __device__ __forceinline__ ZT    to_zt(float v);
template <> __device__ __forceinline__ float  to_zt<float>(float v)  { return v; }
template <> __device__ __forceinline__ __half to_zt<__half>(float v) { return __float2half(v); }
__device__ __forceinline__ float from_zt(float v)  { return v; }
__device__ __forceinline__ float from_zt(__half v) { return __half2float(v); }

// ---------------- x[b][t][k] -> xT[t][k][b] ----------------------------------------
__global__ __launch_bounds__(256) void transpose_x(const float* __restrict__ x,
                                                   float* __restrict__ xT)
{
    __shared__ float tile[32][33];
    const int tileId = blockIdx.x;
    const int bt = tileId & 3;
    const int kt = (tileId >> 2) & 15;
    const int t  = tileId >> 6;
    const int tx = threadIdx.x & 31;
    const int ty = threadIdx.x >> 5;
    #pragma unroll
    for (int r = 0; r < 4; ++r) {
        const int b = bt * 32 + ty + r * 8;
        const int k = kt * 32 + tx;
        tile[ty + r * 8][tx] = x[(size_t)b * (T_ * D_) + (size_t)t * D_ + k];
    }
    __syncthreads();
    #pragma unroll
    for (int r = 0; r < 4; ++r) {
        const int k = kt * 32 + ty + r * 8;
        const int b = bt * 32 + tx;
        xT[((size_t)t * D_ + k) * B_ + b] = tile[tx][ty + r * 8];
    }
}

// ---------------- pack W for zx_gemm: Wpk[blk256][k1024][c8] -----------------------
__global__ __launch_bounds__(1024) void pack_w(const float* __restrict__ wk,
                                               const float* __restrict__ wr,
                                               float* __restrict__ Wpk)
{
    const size_t idx = (size_t)blockIdx.x * 1024 + threadIdx.x;
    const int    c   = (int)(idx & 7);
    const size_t k   = (idx >> 3) & 1023;
    const int    blk = (int)(idx >> 13);
    const int    col = ((c >> 1) << 9) + blk * 2 + (c & 1);
    Wpk[idx] = (k < 512) ? wk[k * G4 + col] : wr[(k - 512) * G4 + col];
}

// ---------------- pack W_r for loop4: Wp3[cu32][k512][c64], c = gate*16+uu ---------
__global__ __launch_bounds__(1024) void pack_w3(const float* __restrict__ wr,
                                                float* __restrict__ Wp3)
{
    const size_t idx = (size_t)blockIdx.x * 1024 + threadIdx.x;  // 1,048,576
    const int c  = (int)(idx & 63);
    const int k  = (int)((idx >> 6) & 511);
    const int cu = (int)(idx >> 15);
    const int col = ((c >> 4) << 9) + cu * 16 + (c & 15);
    Wp3[idx] = wr[(size_t)k * G4 + col];
}

// ---------------- zx[t][g][cu][c][r] = bias + x_t @ Wk  (stage-64) -----------------
template <typename ZT>
__global__ __launch_bounds__(NTHR, 4) void zx_gemm(
    const float* __restrict__ xT, const float* __restrict__ Wpk,
    const float* __restrict__ bias, ZT* __restrict__ zx)
{
    __shared__ float parts[8][128][9];
    __shared__ float bias_l[8];
    const int tid = threadIdx.x, blk = blockIdx.x, u0 = blk * 2;
    if (tid < 8) bias_l[tid] = bias[(tid >> 1) * U_ + u0 + (tid & 1)];
    const int b = tid & 127, ksub = tid >> 7;
    const int ksub_u = __builtin_amdgcn_readfirstlane(ksub);
    const float* __restrict__ wp = Wpk + ((size_t)blk * 1024 + (size_t)ksub_u * 64) * 8;
    __syncthreads();

    for (int t = 0; t < T_; ++t) {
        const float* __restrict__ xp = xT + ((size_t)t * D_ + ksub * 64) * B_ + b;
        float xv[64];
        #pragma unroll
        for (int i = 0; i < 64; ++i) xv[i] = xp[(size_t)i * B_];
        float acc[8] = {0.f,0.f,0.f,0.f,0.f,0.f,0.f,0.f};
        #pragma unroll
        for (int kq = 0; kq < 16; ++kq) {
            const float v0 = xv[kq * 4 + 0];
            const float v1 = xv[kq * 4 + 1];
            const float v2 = xv[kq * 4 + 2];
            const float v3 = xv[kq * 4 + 3];
            const float* __restrict__ w = wp + kq * 32;
            #pragma unroll
            for (int c = 0; c < 8; ++c)
                acc[c] += v0 * w[c] + v1 * w[8 + c] + v2 * w[16 + c] + v3 * w[24 + c];
        }
        #pragma unroll
        for (int c = 0; c < 8; ++c) parts[ksub][b][c] = acc[c];
        __syncthreads();
        {
            const int c = tid >> 7, bb = tid & 127;
            float s = bias_l[c];
            #pragma unroll
            for (int ks = 0; ks < 8; ++ks) s += parts[ks][bb][c];
            // new layout: [t][g][cu][cc][r]
            const int u  = u0 + (c & 1);
            const int cc = ((c >> 1) << 4) + (u & 15);
            const int cu = u >> 4;
            const int g  = bb >> 4, r = bb & 15;
            zx[((((size_t)t * 8 + g) * 32 + cu) * 64 + cc) * 16 + r] = to_zt<ZT>(s);
        }
        __syncthreads();
    }
}

// ---------------- main loop v4: XCD-local row groups -------------------------------
// 8 independent groups (g = blk&7, 16 rows each); 32 CUs per group each owning
// 16 u (64 gate cols). All h/pd/barrier traffic stays within the group (one XCD
// under round-robin dispatch). Plain recurrence; one 32-arrival barrier per step.
// hb layout [g][p][u512][r16]; pd [g][p][512]; ctrl[g*64].
template <typename ZT>
__global__ __launch_bounds__(NTHR, 4) void skiplstm_loop4(
    const ZT* __restrict__ zx, const float* __restrict__ Wp,
    const float* __restrict__ dk, const float* __restrict__ dbp,
    float* __restrict__ out, float* __restrict__ hb,
    float* __restrict__ pd, unsigned* __restrict__ ctrl)
{
    __shared__ float parts[16 * 1088];   // [ks][c*17+r]  68 KB (pad 17)
    __shared__ float hlds[8192];         // [k][r] staged hb(t-1)  32 KB
    __shared__ float red2[512];          // resolve staging
    __shared__ float ut_l[16], ug_l[16];
    __shared__ float dk1_l[16], dk2_l[16];
    __shared__ float db_l;

    const int tid = threadIdx.x;
    const int blk = blockIdx.x;
    const int g   = blk & 7;
    const int cu  = blk >> 3;
    const int u0  = cu * 16;

    float*    __restrict__ hbg  = hb + (size_t)g * (2 * 512 * 16);
    float*    __restrict__ pdg  = pd + (size_t)g * (2 * 512);
    unsigned* __restrict__ barg = ctrl + g * 64;

    if (tid < 16) {
        ut_l[tid] = 1.f; ug_l[tid] = 1.f;
        dk1_l[tid] = dk[u0 + tid];
        dk2_l[tid] = dk[U_ + u0 + tid];
    }
    if (tid == 0) db_l = dbp[0];

    // gate-thread (tid<256) register state: (row gr, unit guu)
    const int gr = tid >> 4, guu = tid & 15;
    float c_st = 0.f, h_st = 0.f;

    // GEMM ids
    const int ksI = tid >> 6, cI = tid & 63;
    const int ks_u = __builtin_amdgcn_readfirstlane(ksI);
    const float* __restrict__ wp = Wp + ((size_t)cu * 512 + (size_t)ks_u * 32) * 64 + cI;

    __syncthreads();

    #pragma unroll 1
    for (int t = 0; t < T_; ++t) {
        // ---- P0: prefetch zx (gate threads), resolve staging, stage hb -> LDS ----
        float zpre[4];
        if (tid < 256) {
            const size_t zb = (((size_t)t * 8 + g) * 32 + cu) * 1024;  // *64*16
            #pragma unroll
            for (int gg = 0; gg < 4; ++gg)
                zpre[gg] = from_zt(zx[zb + (size_t)(gg * 16 + guu) * 16 + gr]);
        }
        if (t > 0 && tid < 512)
            red2[tid] = AGENT_LD(pdg + ((t - 1) & 1) * 512 + tid);
        {
            const float* __restrict__ hsrc = hbg + ((t + 1) & 1) * 8192;
            #pragma unroll
            for (int j = 0; j < 8; ++j)
                hlds[tid + j * 1024] = AGENT_LD(hsrc + tid + j * 1024);
        }
        __syncthreads();

        // ---- P1: GEMM zh = hb(t-1) @ Wr ; lanes 0-15 also resolve delta ----
        if (t > 0 && tid < 16) {
            float s = 0.f;
            #pragma unroll 4
            for (int j = 0; j < 32; ++j) s += red2[j * 16 + tid];
            const float dlt = sigm(s + db_l);
            const float utp = ut_l[tid];
            const float ugp = rintf(utp);
            const float utn = ugp * dlt + (1.f - ugp) * (utp + fminf(dlt, 1.f - utp));
            ut_l[tid] = utn;
            ug_l[tid] = rintf(utn);
        }
        {
            float acc[16];
            #pragma unroll
            for (int r = 0; r < 16; ++r) acc[r] = 0.f;
            #pragma unroll 4
            for (int kk = 0; kk < 32; ++kk) {
                const float w = wp[kk * 64];                       // lane-coalesced
                const float4* __restrict__ h4 =
                    (const float4*)(hlds + (ks_u * 32 + kk) * 16); // wave-uniform bcast
                const float4 a = h4[0], b4 = h4[1], c4 = h4[2], d4 = h4[3];
                acc[0]  += a.x  * w; acc[1]  += a.y  * w; acc[2]  += a.z  * w; acc[3]  += a.w  * w;
                acc[4]  += b4.x * w; acc[5]  += b4.y * w; acc[6]  += b4.z * w; acc[7]  += b4.w * w;
                acc[8]  += c4.x * w; acc[9]  += c4.y * w; acc[10] += c4.z * w; acc[11] += c4.w * w;
                acc[12] += d4.x * w; acc[13] += d4.y * w; acc[14] += d4.z * w; acc[15] += d4.w * w;
            }
            float* pp = parts + ksI * 1088 + cI * 17;
            #pragma unroll
            for (int r = 0; r < 16; ++r) pp[r] = acc[r];
        }
        __syncthreads();

        // ---- P2: gates (tid<256): reduce 16 ksubs per gate col, LSTM math ----
        if (tid < 256) {
            float z[4];
            #pragma unroll
            for (int gg = 0; gg < 4; ++gg) {
                float s = zpre[gg];
                const int c = gg * 16 + guu;
                #pragma unroll
                for (int ks = 0; ks < 16; ++ks) s += parts[ks * 1088 + c * 17 + gr];
                z[gg] = s;
            }
            const float ug = ug_l[gr];
            const float si = sigm(z[0]);
            const float sf = sigm(z[1]);
            const float gt = tanhf(z[2]);
            const float so = sigm(z[3]);
            const float c_n = sf * c_st + si * gt;
            const float h_n = so * tanhf(c_n);
            const float hbv = ug * h_st + (1.f - ug) * h_n;
            const float cbv = ug * c_st + (1.f - ug) * c_n;
            const int b = g * 16 + gr;
            out[(size_t)b * (T_ * U_) + (size_t)t * U_ + u0 + guu] = h_n;
            AGENT_ST(hbg + (t & 1) * 8192 + (size_t)(u0 + guu) * 16 + gr, hbv);
            c_st = cbv; h_st = hbv;
            float p = hbv * dk1_l[guu] + cbv * dk2_l[guu];
            p += __shfl_xor(p, 1);
            p += __shfl_xor(p, 2);
            p += __shfl_xor(p, 4);
            p += __shfl_xor(p, 8);
            if (guu == 0) AGENT_ST(pdg + (t & 1) * 512 + cu * 16 + gr, p);
        }
        __syncthreads();   // drains all stores (compiler emits vmcnt(0) before barrier)

        if (t == T_ - 1) break;

        // ---- P3: group barrier (32 arrivals, one counter per group) ----
        if (tid == 0) {
            __hip_atomic_fetch_add(barg, 1u, __ATOMIC_RELEASE, __HIP_MEMORY_SCOPE_AGENT);
            const unsigned tgt = (unsigned)(32 * (t + 1));
            while (AGENT_LDA(barg) < tgt) __builtin_amdgcn_s_sleep(1);
        }
        __syncthreads();
    }
}

// ---------------- R2 fallback (ws too small): proven 55 ms path --------------------
__global__ __launch_bounds__(NTHR, 4) void skiplstm_kernel_T(
    const float* __restrict__ xT, const float* __restrict__ wk,
    const float* __restrict__ wr, const float* __restrict__ bias,
    const float* __restrict__ dk, const float* __restrict__ dbp,
    float* __restrict__ out, float* __restrict__ hbuf, float* __restrict__ pd)
{
    __shared__ __align__(16) float Wlds[8][1024];
    __shared__ float parts[8][128][9];
    __shared__ float c_state[128][2];
    __shared__ float ut_lds[128];
    __shared__ float bias_l[8];
    __shared__ float dk_l[4];
    __shared__ float db_l;

    const int tid = threadIdx.x;
    const int u0 = blockIdx.x * 2;

    #pragma unroll
    for (int c = 0; c < 8; ++c) {
        const int g = c >> 1, j = c & 1;
        const int gcol = g * U_ + u0 + j;
        Wlds[c][tid] = (tid < D_) ? wk[(size_t)tid * G4 + gcol]
                                  : wr[(size_t)(tid - D_) * G4 + gcol];
    }
    if (tid < 8)  bias_l[tid] = bias[(tid >> 1) * U_ + u0 + (tid & 1)];
    if (tid < 2) { dk_l[tid] = dk[u0 + tid]; dk_l[2 + tid] = dk[U_ + u0 + tid]; }
    if (tid == 0) db_l = dbp[0];
    if (tid < 128) { ut_lds[tid] = 1.0f; c_state[tid][0] = 0.0f; c_state[tid][1] = 0.0f; }
    if (tid < 512) hbuf[blockIdx.x * 512 + tid] = 0.0f;

    cg::grid_group grid = cg::this_grid();
    __syncthreads();
    grid.sync();

    const int b    = tid & 127;
    const int ksub = tid >> 7;

    #pragma unroll 1
    for (int t = 0; t < T_; ++t) {
        const float* __restrict__ hcurT = hbuf + (t & 1) * (U_ * B_);
        float* __restrict__ hnxtT = hbuf + ((t + 1) & 1) * (U_ * B_);

        const float* __restrict__ src = (ksub < 4)
            ? (xT + ((size_t)t * D_ + ksub * 128) * B_ + b)
            : (hcurT + (size_t)(ksub - 4) * 128 * B_ + b);

        float acc[8] = {0.f,0.f,0.f,0.f,0.f,0.f,0.f,0.f};
        #pragma unroll 2
        for (int kq = 0; kq < 32; ++kq) {
            const float v0 = src[(kq * 4 + 0) * B_];
            const float v1 = src[(kq * 4 + 1) * B_];
            const float v2 = src[(kq * 4 + 2) * B_];
            const float v3 = src[(kq * 4 + 3) * B_];
            const int k4 = ksub * 32 + kq;
            #pragma unroll
            for (int c = 0; c < 8; ++c) {
                const float4 w = ((const float4*)(&Wlds[c][0]))[k4];
                acc[c] += v0 * w.x + v1 * w.y + v2 * w.z + v3 * w.w;
            }
        }
        #pragma unroll
        for (int c = 0; c < 8; ++c) parts[ksub][b][c] = acc[c];
        __syncthreads();

        if (tid < 256) {
            const int bb = tid >> 1, j = tid & 1;
            float z[4];
            #pragma unroll
            for (int g = 0; g < 4; ++g) {
                float s = bias_l[g*2 + j];
                #pragma unroll
                for (int ks = 0; ks < 8; ++ks) s += parts[ks][bb][g*2 + j];
                z[g] = s;
            }
            const float ut    = ut_lds[bb];
            const float ug    = rintf(ut);
            const float c_old = c_state[bb][j];
            const float si = sigm(z[0]);
            const float sf = sigm(z[1]);
            const float gg = tanhf(z[2]);
            const float so = sigm(z[3]);
            const float c_n = sf * c_old + si * gg;
            const float h_n = so * tanhf(c_n);
            const float h_old = hcurT[(u0 + j) * B_ + bb];
            const float hbv = ug * h_old + (1.f - ug) * h_n;
            const float cbv = ug * c_old + (1.f - ug) * c_n;
            out[(size_t)bb * (T_ * U_) + (size_t)t * U_ + u0 + j] = h_n;
            hnxtT[(u0 + j) * B_ + bb] = hbv;
            c_state[bb][j] = cbv;
            float p = hbv * dk_l[j] + cbv * dk_l[2 + j];
            p += __shfl_xor(p, 1);
            if (j == 0) pd[(t & 1) * (NBLK * B_) + blockIdx.x * B_ + bb] = p;
        }

        grid.sync();

        {
            const int bb2 = tid >> 3, o = tid & 7;
            const float* __restrict__ pdt = pd + (t & 1) * (NBLK * B_);
            float s = 0.f;
            #pragma unroll 1
            for (int i = 0; i < 32; ++i) s += pdt[(o * 32 + i) * B_ + bb2];
            s += __shfl_xor(s, 1);
            s += __shfl_xor(s, 2);
            s += __shfl_xor(s, 4);
            if (o == 0) {
                const float delta = sigm(s + db_l);
                const float ut = ut_lds[bb2];
                const float ug = rintf(ut);
                ut_lds[bb2] = ug * delta + (1.f - ug) * (ut + fminf(delta, 1.f - ut));
            }
        }
        __syncthreads();
    }
}

// ---------------- host -------------------------------------------------------------
extern "C" void kernel_launch(void* const* d_in, const int* in_sizes, int n_in,
                              void* d_out, int out_size, void* d_ws, size_t ws_size,
                              hipStream_t stream)
{
    (void)in_sizes; (void)n_in; (void)out_size;
    const float* x  = (const float*)d_in[0];
    const float* wk = (const float*)d_in[1];
    const float* wr = (const float*)d_in[2];
    const float* bs = (const float*)d_in[3];
    const float* dk = (const float*)d_in[4];
    const float* db = (const float*)d_in[5];
    float* out = (float*)d_out;

    const size_t xT_b   = (size_t)T_ * D_ * B_ * 4;          // 256 MiB
    const size_t wpk_b  = (size_t)NBLK * 1024 * 8 * 4;       // 8 MiB
    const size_t wp3_b  = (size_t)32 * 512 * 64 * 4;         // 4 MiB
    const size_t hb_b   = (size_t)8 * 2 * 512 * 16 * 4;      // 512 KiB
    const size_t pd_b   = (size_t)8 * 2 * 512 * 4;           // 32 KiB
    const size_t ctrl_b = 8 * 64 * 4;                        // 2 KiB
    const size_t zx32_b = (size_t)T_ * G4 * B_ * 4;          // 1 GiB
    const size_t zx16_b = zx32_b / 2;                        // 512 MiB
    const size_t tail_b = hb_b + pd_b + ctrl_b;

    const size_t need_A = zx32_b + xT_b + wpk_b + wp3_b + tail_b;
    const size_t need_B = zx16_b + xT_b + wpk_b + wp3_b + tail_b;

    char* w = (char*)d_ws;

    if (ws_size >= need_B) {
        const bool f32zx = (ws_size >= need_A);
        const size_t zx_b = f32zx ? zx32_b : zx16_b;
        char*  zxp  = w;
        float* xT   = (float*)(w + zx_b);
        float* Wpk  = (float*)(w + zx_b + xT_b);
        float* Wp3  = (float*)(w + zx_b + xT_b + wpk_b);
        float* hb   = (float*)(w + zx_b + xT_b + wpk_b + wp3_b);
        float* pd   = (float*)(w + zx_b + xT_b + wpk_b + wp3_b + hb_b);
        unsigned* ctrl = (unsigned*)(w + zx_b + xT_b + wpk_b + wp3_b + hb_b + pd_b);

        hipMemsetAsync(hb, 0, tail_b, stream);
        transpose_x<<<dim3(T_ * 16 * 4), dim3(256), 0, stream>>>(x, xT);
        pack_w<<<dim3(2048), dim3(1024), 0, stream>>>(wk, wr, Wpk);
        pack_w3<<<dim3(1024), dim3(1024), 0, stream>>>(wr, Wp3);

        if (f32zx) {
            float* zx = (float*)zxp;
            zx_gemm<float><<<dim3(NBLK), dim3(NTHR), 0, stream>>>(xT, Wpk, bs, zx);
            void* args[] = { (void*)&zx, (void*)&Wp3, (void*)&dk, (void*)&db,
                             (void*)&out, (void*)&hb, (void*)&pd, (void*)&ctrl };
            hipLaunchCooperativeKernel(reinterpret_cast<void*>(skiplstm_loop4<float>),
                                       dim3(NBLK), dim3(NTHR), args, 0, stream);
        } else {
            __half* zx = (__half*)zxp;
            zx_gemm<__half><<<dim3(NBLK), dim3(NTHR), 0, stream>>>(xT, Wpk, bs, zx);
            void* args[] = { (void*)&zx, (void*)&Wp3, (void*)&dk, (void*)&db,
                             (void*)&out, (void*)&hb, (void*)&pd, (void*)&ctrl };
            hipLaunchCooperativeKernel(reinterpret_cast<void*>(skiplstm_loop4<__half>),
                                       dim3(NBLK), dim3(NTHR), args, 0, stream);
        }
    } else {
        float* xT   = (float*)d_ws;
        float* hbuf = xT + (size_t)T_ * D_ * B_;
        float* pd   = hbuf + 2 * U_ * B_;
        transpose_x<<<dim3(T_ * 16 * 4), dim3(256), 0, stream>>>(x, xT);
        void* args[] = { (void*)&xT, (void*)&wk, (void*)&wr, (void*)&bs, (void*)&dk, (void*)&db,
                         (void*)&out, (void*)&hbuf, (void*)&pd };
        hipLaunchCooperativeKernel(reinterpret_cast<void*>(skiplstm_kernel_T),
                                   dim3(NBLK), dim3(NTHR), args, 0, stream);
    }
}

// Round 10
// 34016.495 us; speedup vs baseline: 1.5968x; 1.0327x over previous
//
#include <hip/hip_runtime.h>
#include <hip/hip_fp16.h>
#include <hip/hip_cooperative_groups.h>

namespace cg = cooperative_groups;

constexpr int B_ = 128, T_ = 1024, D_ = 512, U_ = 512;
constexpr int NBLK = 256, NTHR = 1024;
constexpr int G4 = 4 * U_;   // 2048 gate columns

__device__ __forceinline__ float sigm(float v) { return 1.0f / (1.0f + expf(-v)); }

#define AGENT_LD(p)    __hip_atomic_load((p), __ATOMIC_RELAXED, __HIP_MEMORY_SCOPE_AGENT)
#define AGENT_LDA(p)   __hip_atomic_load((p), __ATOMIC_ACQUIRE, __HIP_MEMORY_SCOPE_AGENT)
#define AGENT_ST(p, v) __hip_atomic_store((p), (v), __ATOMIC_RELAXED, __HIP_MEMORY_SCOPE_AGENT)

template <typename ZT> __device__ __forceinline__ ZT    to_zt(float v);
template <> __device__ __forceinline__ float  to_zt<float>(float v)  { return v; }
template <> __device__ __forceinline__ __half to_zt<__half>(float v) { return __float2half(v); }
__device__ __forceinline__ float from_zt(float v)  { return v; }
__device__ __forceinline__ float from_zt(__half v) { return __half2float(v); }

__device__ __forceinline__ float bcast_lane(float v, int lane) {
    return __int_as_float(__builtin_amdgcn_readlane(__float_as_int(v), lane));
}

// ---------------- x[b][t][k] -> xT[t][k][b] ----------------------------------------
__global__ __launch_bounds__(256) void transpose_x(const float* __restrict__ x,
                                                   float* __restrict__ xT)
{
    __shared__ float tile[32][33];
    const int tileId = blockIdx.x;
    const int bt = tileId & 3;
    const int kt = (tileId >> 2) & 15;
    const int t  = tileId >> 6;
    const int tx = threadIdx.x & 31;
    const int ty = threadIdx.x >> 5;
    #pragma unroll
    for (int r = 0; r < 4; ++r) {
        const int b = bt * 32 + ty + r * 8;
        const int k = kt * 32 + tx;
        tile[ty + r * 8][tx] = x[(size_t)b * (T_ * D_) + (size_t)t * D_ + k];
    }
    __syncthreads();
    #pragma unroll
    for (int r = 0; r < 4; ++r) {
        const int k = kt * 32 + ty + r * 8;
        const int b = bt * 32 + tx;
        xT[((size_t)t * D_ + k) * B_ + b] = tile[tx][ty + r * 8];
    }
}

// ---------------- pack W for zx_gemm: Wpk[blk256][k1024][c8] -----------------------
__global__ __launch_bounds__(1024) void pack_w(const float* __restrict__ wk,
                                               const float* __restrict__ wr,
                                               float* __restrict__ Wpk)
{
    const size_t idx = (size_t)blockIdx.x * 1024 + threadIdx.x;
    const int    c   = (int)(idx & 7);
    const size_t k   = (idx >> 3) & 1023;
    const int    blk = (int)(idx >> 13);
    const int    col = ((c >> 1) << 9) + blk * 2 + (c & 1);
    Wpk[idx] = (k < 512) ? wk[k * G4 + col] : wr[(k - 512) * G4 + col];
}

// ---------------- pack W_r for loop5: Wp3[cu32][k512][c64], col = (c>>4)*512+cu*16+(c&15)
__global__ __launch_bounds__(1024) void pack_w3(const float* __restrict__ wr,
                                                float* __restrict__ Wp3)
{
    const size_t idx = (size_t)blockIdx.x * 1024 + threadIdx.x;  // 1,048,576
    const int c  = (int)(idx & 63);
    const int k  = (int)((idx >> 6) & 511);
    const int cu = (int)(idx >> 15);
    const int col = ((c >> 4) << 9) + cu * 16 + (c & 15);
    Wp3[idx] = wr[(size_t)k * G4 + col];
}

// ---------------- zx[t][gc][b] = bias + x_t @ Wk  (R3/R8-proven, coalesced writes) --
template <typename ZT>
__global__ __launch_bounds__(NTHR, 4) void zx_gemm(
    const float* __restrict__ xT, const float* __restrict__ Wpk,
    const float* __restrict__ bias, ZT* __restrict__ zx)
{
    __shared__ float parts[8][128][9];
    __shared__ float bias_l[8];
    const int tid = threadIdx.x, blk = blockIdx.x, u0 = blk * 2;
    if (tid < 8) bias_l[tid] = bias[(tid >> 1) * U_ + u0 + (tid & 1)];
    const int b = tid & 127, ksub = tid >> 7;
    const int ksub_u = __builtin_amdgcn_readfirstlane(ksub);
    const float* __restrict__ wp = Wpk + ((size_t)blk * 1024 + (size_t)ksub_u * 64) * 8;
    __syncthreads();

    for (int t = 0; t < T_; ++t) {
        const float* __restrict__ xp = xT + ((size_t)t * D_ + ksub * 64) * B_ + b;
        float xv[64];
        #pragma unroll
        for (int i = 0; i < 64; ++i) xv[i] = xp[(size_t)i * B_];
        float acc[8] = {0.f,0.f,0.f,0.f,0.f,0.f,0.f,0.f};
        #pragma unroll
        for (int kq = 0; kq < 16; ++kq) {
            const float v0 = xv[kq * 4 + 0];
            const float v1 = xv[kq * 4 + 1];
            const float v2 = xv[kq * 4 + 2];
            const float v3 = xv[kq * 4 + 3];
            const float* __restrict__ w = wp + kq * 32;
            #pragma unroll
            for (int c = 0; c < 8; ++c)
                acc[c] += v0 * w[c] + v1 * w[8 + c] + v2 * w[16 + c] + v3 * w[24 + c];
        }
        #pragma unroll
        for (int c = 0; c < 8; ++c) parts[ksub][b][c] = acc[c];
        __syncthreads();
        {
            const int c = tid >> 7, bb = tid & 127;
            float s = bias_l[c];
            #pragma unroll
            for (int ks = 0; ks < 8; ++ks) s += parts[ks][bb][c];
            zx[((size_t)t * G4 + (c >> 1) * U_ + u0 + (c & 1)) * B_ + bb] = to_zt<ZT>(s);
        }
        __syncthreads();
    }
}

// ---------------- main loop v5: group-local + W-in-regs + readlane h-broadcast -----
// 8 groups (g=blk&7) x 16 rows; CU (cu=blk>>3) owns 16 u = 64 gate cols.
// GEMM thread (ksI 0..15, cI 0..63): W 32 floats in VGPRs (t-invariant);
// h: wave loads its 2KB slice coalesced into 8 VGPR/lane, broadcast via v_readlane.
// Gate thread (guu=tid>>4, gr=tid&15) keeps h/c state in registers.
// hb layout [g][p][u512][r16]; pd [g][p][512]; ctrl[g*64].
template <typename ZT>
__global__ __launch_bounds__(NTHR, 4) void skiplstm_loop5(
    const ZT* __restrict__ zx, const float* __restrict__ Wp,
    const float* __restrict__ dk, const float* __restrict__ dbp,
    float* __restrict__ out, float* __restrict__ hb,
    float* __restrict__ pd, unsigned* __restrict__ ctrl)
{
    __shared__ float parts[16 * 1088];   // [ks][c*17+r]  68 KB
    __shared__ float pdl[16][17];
    __shared__ float ut_l[16], ug_l[16];
    __shared__ float dk1_l[16], dk2_l[16];
    __shared__ float db_l;

    const int tid = threadIdx.x;
    const int blk = blockIdx.x;
    const int g   = blk & 7;
    const int cu  = blk >> 3;
    const int u0  = cu * 16;

    float*    __restrict__ hbg  = hb + (size_t)g * (2 * 512 * 16);
    float*    __restrict__ pdg  = pd + (size_t)g * (2 * 512);
    unsigned* __restrict__ barg = ctrl + g * 64;

    if (tid < 16) {
        ut_l[tid] = 1.f; ug_l[tid] = 1.f;
        dk1_l[tid] = dk[u0 + tid];
        dk2_l[tid] = dk[U_ + u0 + tid];
    }
    if (tid == 0) db_l = dbp[0];

    // gate-thread state (row gr, unit guu)
    const int guu = (tid >> 4) & 15, gr = tid & 15;
    float c_st = 0.f, h_st = 0.f;

    // GEMM ids + W in registers (t-invariant)
    const int ksI  = tid >> 6, cI = tid & 63;
    const int ks_u = __builtin_amdgcn_readfirstlane(ksI);
    float w_reg[32];
    {
        const float* __restrict__ wsrc = Wp + ((size_t)cu * 512 + (size_t)ks_u * 32) * 64 + cI;
        #pragma unroll
        for (int kk = 0; kk < 32; ++kk) w_reg[kk] = wsrc[kk * 64];
    }
    __syncthreads();

    #pragma unroll 1
    for (int t = 0; t < T_; ++t) {
        // ---- P0: issue zx prefetch (gate threads) + h slice loads (all) ----
        float zpre[4];
        if (tid < 256) {
            const ZT* __restrict__ zb =
                zx + ((size_t)t * G4 + u0 + guu) * B_ + g * 16 + gr;
            #pragma unroll
            for (int gg = 0; gg < 4; ++gg)
                zpre[gg] = from_zt(zb[(size_t)gg * 512 * B_]);
        }
        float h_reg[8];
        {
            const float* __restrict__ hsrc =
                hbg + ((t + 1) & 1) * 8192 + ks_u * 512;
            #pragma unroll
            for (int j = 0; j < 8; ++j)
                h_reg[j] = AGENT_LD(hsrc + j * 64 + cI);
        }

        // ---- P1a: resolve delta(t-1) (wave0 lanes 0-15; others go to GEMM) ----
        if (t > 0 && tid < 16) {
            const float* __restrict__ pdt = pdg + ((t - 1) & 1) * 512;
            float s = 0.f;
            #pragma unroll
            for (int c2 = 0; c2 < 32; ++c2) s += AGENT_LD(pdt + c2 * 16 + tid);
            const float dlt = sigm(s + db_l);
            const float utp = ut_l[tid];
            const float ugp = rintf(utp);
            const float utn = ugp * dlt + (1.f - ugp) * (utp + fminf(dlt, 1.f - utp));
            ut_l[tid] = utn;
            ug_l[tid] = rintf(utn);
        }

        // ---- P1b: GEMM zh = hb(t-1) @ Wr via readlane broadcast ----
        {
            float acc[16];
            #pragma unroll
            for (int r = 0; r < 16; ++r) acc[r] = 0.f;
            #pragma unroll
            for (int kk = 0; kk < 32; ++kk) {
                const float w = w_reg[kk];
                #pragma unroll
                for (int r = 0; r < 16; ++r) {
                    const float hv = bcast_lane(h_reg[kk >> 2], ((kk & 3) << 4) | r);
                    acc[r] += hv * w;
                }
            }
            float* __restrict__ pp = parts + ksI * 1088 + cI * 17;
            #pragma unroll
            for (int r = 0; r < 16; ++r) pp[r] = acc[r];
        }
        __syncthreads();   // parts + ug_l ready (zx/h loads drained)

        // ---- P2: gates (tid<256) ----
        if (tid < 256) {
            float z[4];
            #pragma unroll
            for (int gg = 0; gg < 4; ++gg) {
                float s = zpre[gg];
                const int c = gg * 16 + guu;
                #pragma unroll
                for (int ks = 0; ks < 16; ++ks) s += parts[ks * 1088 + c * 17 + gr];
                z[gg] = s;
            }
            const float ug = ug_l[gr];
            const float si = sigm(z[0]);
            const float sf = sigm(z[1]);
            const float gt = tanhf(z[2]);
            const float so = sigm(z[3]);
            const float c_n = sf * c_st + si * gt;
            const float h_n = so * tanhf(c_n);
            const float hbv = ug * h_st + (1.f - ug) * h_n;
            const float cbv = ug * c_st + (1.f - ug) * c_n;
            const int b = g * 16 + gr;
            out[(size_t)b * (T_ * U_) + (size_t)t * U_ + u0 + guu] = h_n;
            AGENT_ST(hbg + (t & 1) * 8192 + (size_t)(u0 + guu) * 16 + gr, hbv);
            c_st = cbv; h_st = hbv;
            pdl[guu][gr] = hbv * dk1_l[guu] + cbv * dk2_l[guu];
        }
        __syncthreads();   // pdl ready; all stores drained per-wave

        if (t == T_ - 1) break;

        // ---- P2b: per-CU pd reduce (wave0) + store; arrive orders after it ----
        if (tid < 16) {
            float s = pdl[0][tid];
            #pragma unroll
            for (int j = 1; j < 16; ++j) s += pdl[j][tid];
            AGENT_ST(pdg + (t & 1) * 512 + cu * 16 + tid, s);
        }

        // ---- P3: group barrier (32 arrivals) ----
        if (tid == 0) {
            __hip_atomic_fetch_add(barg, 1u, __ATOMIC_RELEASE, __HIP_MEMORY_SCOPE_AGENT);
            const unsigned tgt = (unsigned)(32 * (t + 1));
            while (AGENT_LDA(barg) < tgt) __builtin_amdgcn_s_sleep(1);
        }
        __syncthreads();
    }
}

// ---------------- R2 fallback (ws too small): proven 55 ms path --------------------
__global__ __launch_bounds__(NTHR, 4) void skiplstm_kernel_T(
    const float* __restrict__ xT, const float* __restrict__ wk,
    const float* __restrict__ wr, const float* __restrict__ bias,
    const float* __restrict__ dk, const float* __restrict__ dbp,
    float* __restrict__ out, float* __restrict__ hbuf, float* __restrict__ pd)
{
    __shared__ __align__(16) float Wlds[8][1024];
    __shared__ float parts[8][128][9];
    __shared__ float c_state[128][2];
    __shared__ float ut_lds[128];
    __shared__ float bias_l[8];
    __shared__ float dk_l[4];
    __shared__ float db_l;

    const int tid = threadIdx.x;
    const int u0 = blockIdx.x * 2;

    #pragma unroll
    for (int c = 0; c < 8; ++c) {
        const int g = c >> 1, j = c & 1;
        const int gcol = g * U_ + u0 + j;
        Wlds[c][tid] = (tid < D_) ? wk[(size_t)tid * G4 + gcol]
                                  : wr[(size_t)(tid - D_) * G4 + gcol];
    }
    if (tid < 8)  bias_l[tid] = bias[(tid >> 1) * U_ + u0 + (tid & 1)];
    if (tid < 2) { dk_l[tid] = dk[u0 + tid]; dk_l[2 + tid] = dk[U_ + u0 + tid]; }
    if (tid == 0) db_l = dbp[0];
    if (tid < 128) { ut_lds[tid] = 1.0f; c_state[tid][0] = 0.0f; c_state[tid][1] = 0.0f; }
    if (tid < 512) hbuf[blockIdx.x * 512 + tid] = 0.0f;

    cg::grid_group grid = cg::this_grid();
    __syncthreads();
    grid.sync();

    const int b    = tid & 127;
    const int ksub = tid >> 7;

    #pragma unroll 1
    for (int t = 0; t < T_; ++t) {
        const float* __restrict__ hcurT = hbuf + (t & 1) * (U_ * B_);
        float* __restrict__ hnxtT = hbuf + ((t + 1) & 1) * (U_ * B_);

        const float* __restrict__ src = (ksub < 4)
            ? (xT + ((size_t)t * D_ + ksub * 128) * B_ + b)
            : (hcurT + (size_t)(ksub - 4) * 128 * B_ + b);

        float acc[8] = {0.f,0.f,0.f,0.f,0.f,0.f,0.f,0.f};
        #pragma unroll 2
        for (int kq = 0; kq < 32; ++kq) {
            const float v0 = src[(kq * 4 + 0) * B_];
            const float v1 = src[(kq * 4 + 1) * B_];
            const float v2 = src[(kq * 4 + 2) * B_];
            const float v3 = src[(kq * 4 + 3) * B_];
            const int k4 = ksub * 32 + kq;
            #pragma unroll
            for (int c = 0; c < 8; ++c) {
                const float4 w = ((const float4*)(&Wlds[c][0]))[k4];
                acc[c] += v0 * w.x + v1 * w.y + v2 * w.z + v3 * w.w;
            }
        }
        #pragma unroll
        for (int c = 0; c < 8; ++c) parts[ksub][b][c] = acc[c];
        __syncthreads();

        if (tid < 256) {
            const int bb = tid >> 1, j = tid & 1;
            float z[4];
            #pragma unroll
            for (int g = 0; g < 4; ++g) {
                float s = bias_l[g*2 + j];
                #pragma unroll
                for (int ks = 0; ks < 8; ++ks) s += parts[ks][bb][g*2 + j];
                z[g] = s;
            }
            const float ut    = ut_lds[bb];
            const float ug    = rintf(ut);
            const float c_old = c_state[bb][j];
            const float si = sigm(z[0]);
            const float sf = sigm(z[1]);
            const float gg = tanhf(z[2]);
            const float so = sigm(z[3]);
            const float c_n = sf * c_old + si * gg;
            const float h_n = so * tanhf(c_n);
            const float h_old = hcurT[(u0 + j) * B_ + bb];
            const float hbv = ug * h_old + (1.f - ug) * h_n;
            const float cbv = ug * c_old + (1.f - ug) * c_n;
            out[(size_t)bb * (T_ * U_) + (size_t)t * U_ + u0 + j] = h_n;
            hnxtT[(u0 + j) * B_ + bb] = hbv;
            c_state[bb][j] = cbv;
            float p = hbv * dk_l[j] + cbv * dk_l[2 + j];
            p += __shfl_xor(p, 1);
            if (j == 0) pd[(t & 1) * (NBLK * B_) + blockIdx.x * B_ + bb] = p;
        }

        grid.sync();

        {
            const int bb2 = tid >> 3, o = tid & 7;
            const float* __restrict__ pdt = pd + (t & 1) * (NBLK * B_);
            float s = 0.f;
            #pragma unroll 1
            for (int i = 0; i < 32; ++i) s += pdt[(o * 32 + i) * B_ + bb2];
            s += __shfl_xor(s, 1);
            s += __shfl_xor(s, 2);
            s += __shfl_xor(s, 4);
            if (o == 0) {
                const float delta = sigm(s + db_l);
                const float ut = ut_lds[bb2];
                const float ug = rintf(ut);
                ut_lds[bb2] = ug * delta + (1.f - ug) * (ut + fminf(delta, 1.f - ut));
            }
        }
        __syncthreads();
    }
}

// ---------------- host -------------------------------------------------------------
extern "C" void kernel_launch(void* const* d_in, const int* in_sizes, int n_in,
                              void* d_out, int out_size, void* d_ws, size_t ws_size,
                              hipStream_t stream)
{
    (void)in_sizes; (void)n_in; (void)out_size;
    const float* x  = (const float*)d_in[0];
    const float* wk = (const float*)d_in[1];
    const float* wr = (const float*)d_in[2];
    const float* bs = (const float*)d_in[3];
    const float* dk = (const float*)d_in[4];
    const float* db = (const float*)d_in[5];
    float* out = (float*)d_out;

    const size_t xT_b   = (size_t)T_ * D_ * B_ * 4;          // 256 MiB
    const size_t wpk_b  = (size_t)NBLK * 1024 * 8 * 4;       // 8 MiB
    const size_t wp3_b  = (size_t)32 * 512 * 64 * 4;         // 4 MiB
    const size_t hb_b   = (size_t)8 * 2 * 512 * 16 * 4;      // 512 KiB
    const size_t pd_b   = (size_t)8 * 2 * 512 * 4;           // 32 KiB
    const size_t ctrl_b = 8 * 64 * 4;                        // 2 KiB
    const size_t zx32_b = (size_t)T_ * G4 * B_ * 4;          // 1 GiB
    const size_t zx16_b = zx32_b / 2;                        // 512 MiB
    const size_t tail_b = hb_b + pd_b + ctrl_b;

    const size_t need_A = zx32_b + xT_b + wpk_b + wp3_b + tail_b;
    const size_t need_B = zx16_b + xT_b + wpk_b + wp3_b + tail_b;

    char* w = (char*)d_ws;

    if (ws_size >= need_B) {
        const bool f32zx = (ws_size >= need_A);
        const size_t zx_b = f32zx ? zx32_b : zx16_b;
        char*  zxp  = w;
        float* xT   = (float*)(w + zx_b);
        float* Wpk  = (float*)(w + zx_b + xT_b);
        float* Wp3  = (float*)(w + zx_b + xT_b + wpk_b);
        float* hb   = (float*)(w + zx_b + xT_b + wpk_b + wp3_b);
        float* pd   = (float*)(w + zx_b + xT_b + wpk_b + wp3_b + hb_b);
        unsigned* ctrl = (unsigned*)(w + zx_b + xT_b + wpk_b + wp3_b + hb_b + pd_b);

        hipMemsetAsync(hb, 0, tail_b, stream);
        transpose_x<<<dim3(T_ * 16 * 4), dim3(256), 0, stream>>>(x, xT);
        pack_w<<<dim3(2048), dim3(1024), 0, stream>>>(wk, wr, Wpk);
        pack_w3<<<dim3(1024), dim3(1024), 0, stream>>>(wr, Wp3);

        if (f32zx) {
            float* zx = (float*)zxp;
            zx_gemm<float><<<dim3(NBLK), dim3(NTHR), 0, stream>>>(xT, Wpk, bs, zx);
            void* args[] = { (void*)&zx, (void*)&Wp3, (void*)&dk, (void*)&db,
                             (void*)&out, (void*)&hb, (void*)&pd, (void*)&ctrl };
            hipLaunchCooperativeKernel(reinterpret_cast<void*>(skiplstm_loop5<float>),
                                       dim3(NBLK), dim3(NTHR), args, 0, stream);
        } else {
            __half* zx = (__half*)zxp;
            zx_gemm<__half><<<dim3(NBLK), dim3(NTHR), 0, stream>>>(xT, Wpk, bs, zx);
            void* args[] = { (void*)&zx, (void*)&Wp3, (void*)&dk, (void*)&db,
                             (void*)&out, (void*)&hb, (void*)&pd, (void*)&ctrl };
            hipLaunchCooperativeKernel(reinterpret_cast<void*>(skiplstm_loop5<__half>),
                                       dim3(NBLK), dim3(NTHR), args, 0, stream);
        }
    } else {
        float* xT   = (float*)d_ws;
        float* hbuf = xT + (size_t)T_ * D_ * B_;
        float* pd   = hbuf + 2 * U_ * B_;
        transpose_x<<<dim3(T_ * 16 * 4), dim3(256), 0, stream>>>(x, xT);
        void* args[] = { (void*)&xT, (void*)&wk, (void*)&wr, (void*)&bs, (void*)&dk, (void*)&db,
                         (void*)&out, (void*)&hbuf, (void*)&pd };
        hipLaunchCooperativeKernel(reinterpret_cast<void*>(skiplstm_kernel_T),
                                   dim3(NBLK), dim3(NTHR), args, 0, stream);
    }
}